// Round 1
// baseline (328.907 us; speedup 1.0000x reference)
//
#include <hip/hip_runtime.h>
#include <hip/hip_bf16.h>

#define N        8192
#define W        128          // 64-bit words per adjacency row
#define NCLS     5
#define NCOLS    10
#define MIN_PTS  10
#define EPS2     0.0144f      // 0.12^2
#define SENT     N

// ---- persistent device scratch (rewritten every call; avoids ws_size assumptions) ----
__device__ float4             g_pts[N];            // x, y, z, sq
__device__ int                g_cls[N];
__device__ int                g_deg[N];
__device__ int                g_parent[N];
__device__ int                g_pointroot[N];      // component-min root per point, SENT if noise
__device__ int                g_rootlabel[N];      // cluster id for root indices
__device__ unsigned long long g_adj[N * W];        // 8 MB adjacency bitmask
__device__ unsigned long long g_coremask[W];
__device__ unsigned long long g_rootmask[NCLS][W];

// ---------------- union-find ----------------
__device__ __forceinline__ int find_atomic(int v) {
    for (;;) {
        int p = __hip_atomic_load(&g_parent[v], __ATOMIC_RELAXED, __HIP_MEMORY_SCOPE_AGENT);
        if (p == v) return v;
        v = p;
    }
}
__device__ __forceinline__ int find_plain(int v) {
    int p = g_parent[v];
    while (p != v) { v = p; p = g_parent[v]; }
    return v;
}
__device__ void unite(int a, int b) {
    int ra = find_atomic(a), rb = find_atomic(b);
    while (ra != rb) {
        int hi = ra > rb ? ra : rb;
        int lo = ra < rb ? ra : rb;
        int old = atomicCAS(&g_parent[hi], hi, lo);   // only hook a live root
        if (old == hi) return;
        ra = find_atomic(old);
        rb = find_atomic(lo);
    }
}

// ---------------- A: per-point setup + scratch init ----------------
__global__ void k_setup(const float* __restrict__ x) {
    int i = blockIdx.x * blockDim.x + threadIdx.x;
    if (i >= N) return;
    const float* r = x + i * NCOLS;
    float c0 = r[0], c1 = r[1], c2 = r[2];
    // argmax over seg cols 5..9, first max wins (matches jnp.argmax)
    float best = r[5]; int bi = 0;
#pragma unroll
    for (int c = 1; c < NCLS; ++c) {
        float v = r[5 + c];
        if (v > best) { best = v; bi = c; }
    }
    // sq = (c0^2 + c1^2) + c2^2 with NO fma contraction (match numpy elementwise+sum)
    float sq = __fadd_rn(__fadd_rn(__fmul_rn(c0, c0), __fmul_rn(c1, c1)), __fmul_rn(c2, c2));
    g_pts[i] = make_float4(c0, c1, c2, sq);
    g_cls[i] = bi;
    g_parent[i] = i;
    g_pointroot[i] = SENT;
    g_rootlabel[i] = -1;
    if (i < W) g_coremask[i] = 0ull;
    if (i < NCLS * W) ((unsigned long long*)g_rootmask)[i] = 0ull;
}

// ---------------- B: adjacency bitmask + degree (one wave per row) ----------------
__global__ void k_adj() {
    int wave = threadIdx.x >> 6;             // 4 waves/block
    int lane = threadIdx.x & 63;
    int i = blockIdx.x * 4 + wave;
    float4 p = g_pts[i];
    int ci = g_cls[i];
    int deg = 0;
    for (int w = 0; w < W; ++w) {
        int j = (w << 6) + lane;             // lane-coalesced column sweep
        float4 q = g_pts[j];
        int cj = g_cls[j];
        // dot as fma chain (BLAS K=3 accumulation); 2*dot exact, one rounding on subtract
        float dot = __builtin_fmaf(p.z, q.z,
                    __builtin_fmaf(p.y, q.y,
                    __builtin_fmaf(p.x, q.x, 0.0f)));
        float d2 = (p.w + q.w) - 2.0f * dot;
        bool adjb = (d2 < EPS2) && (ci == cj);   // diagonal included (d2_ii ~ 0)
        unsigned long long word = __ballot(adjb);
        if (lane == 0) {
            g_adj[i * W + w] = word;
            deg += __popcll(word);
        }
    }
    if (lane == 0) g_deg[i] = deg;
}

// ---------------- C: pack core bitmask ----------------
__global__ void k_core() {
    int w = threadIdx.x;                     // 128 threads, 1 block
    unsigned long long m = 0ull;
    for (int k = 0; k < 64; ++k)
        if (g_deg[(w << 6) + k] >= MIN_PTS) m |= (1ull << k);
    g_coremask[w] = m;
}

// ---------------- D: union all core-core edges (j < i) ----------------
__global__ void k_union() {
    __shared__ unsigned long long s_core[W];
    int t = threadIdx.x;
    if (t < W) s_core[t] = g_coremask[t];
    __syncthreads();
    int gid = blockIdx.x * blockDim.x + t;
    int i = gid >> 7, w = gid & 127;
    if (g_deg[i] < MIN_PTS) return;          // i must be core
    int jbase = w << 6;
    if (jbase >= i) return;                  // each unordered pair once (symmetric adj)
    unsigned long long word = g_adj[i * W + w] & s_core[w];
    int lim = i - jbase;
    if (lim < 64) word &= (1ull << lim) - 1; // keep j < i
    while (word) {
        int k = __builtin_ctzll(word);
        word &= word - 1;
        unite(i, jbase + k);
    }
}

// ---------------- E: point roots + root bitmask ----------------
__global__ void k_pointroot() {
    __shared__ unsigned long long s_core[W];
    int t = threadIdx.x;
    if (t < W) s_core[t] = g_coremask[t];
    __syncthreads();
    int gid = blockIdx.x * blockDim.x + t;
    int i = gid >> 7, w = gid & 127;
    bool corei = (g_deg[i] >= MIN_PTS);
    if (corei) {
        if (w == 0) {
            int r = find_plain(i);           // parent stable after k_union
            g_pointroot[i] = r;
            if (r == i)                      // is_root: core && comp==idx
                atomicOr(&g_rootmask[g_cls[i]][i >> 6], 1ull << (i & 63));
        }
        return;
    }
    // border/noise: min over core neighbors' component roots
    unsigned long long word = g_adj[i * W + w] & s_core[w];
    while (word) {
        int k = __builtin_ctzll(word);
        word &= word - 1;
        atomicMin(&g_pointroot[i], find_plain((w << 6) + k));
    }
}

// ---------------- G: cluster ids = rank of root key (class*N + idx) ----------------
__global__ void k_rootlabel() {
    int i = blockIdx.x * blockDim.x + threadIdx.x;
    if (i >= N) return;
    if (g_deg[i] < MIN_PTS || g_pointroot[i] != i) return;   // roots only
    int c = g_cls[i];
    int cnt = 0;
    for (int cc = 0; cc < c; ++cc)
#pragma unroll 8
        for (int w = 0; w < W; ++w) cnt += __popcll(g_rootmask[cc][w]);
    int wi = i >> 6;
    for (int w = 0; w < wi; ++w) cnt += __popcll(g_rootmask[c][w]);
    cnt += __popcll(g_rootmask[c][wi] & ((1ull << (i & 63)) - 1));
    g_rootlabel[i] = cnt;
}

// ---------------- H: emit outputs ----------------
__global__ void k_output(const float* __restrict__ x, float* __restrict__ out) {
    int i = blockIdx.x * blockDim.x + threadIdx.x;
    if (i >= N) return;
    int pr = g_pointroot[i];
    bool clustered = (pr < SENT);
    float o[6] = {0.f, 0.f, 0.f, 0.f, 0.f, 0.f};
    float lab = -1.0f;
    if (clustered) {
        lab = (float)g_rootlabel[pr];
        const float* r = x + i * NCOLS;
#pragma unroll
        for (int k = 0; k < 5; ++k) o[k] = r[k];
        o[5] = (float)g_cls[i];
    }
    float* orow = out + i * 6;
#pragma unroll
    for (int k = 0; k < 6; ++k) orow[k] = o[k];
    out[N * 6 + i] = lab;                    // labels as f32 (single-dtype flat buffer)
}

extern "C" void kernel_launch(void* const* d_in, const int* in_sizes, int n_in,
                              void* d_out, int out_size, void* d_ws, size_t ws_size,
                              hipStream_t stream) {
    const float* x = (const float*)d_in[0];
    float* out = (float*)d_out;
    (void)in_sizes; (void)n_in; (void)out_size; (void)d_ws; (void)ws_size;

    k_setup    <<<N / 256, 256, 0, stream>>>(x);
    k_adj      <<<N / 4,   256, 0, stream>>>();        // 4 waves/block, wave per row
    k_core     <<<1,       128, 0, stream>>>();
    k_union    <<<(N * W) / 256, 256, 0, stream>>>();
    k_pointroot<<<(N * W) / 256, 256, 0, stream>>>();
    k_rootlabel<<<N / 256, 256, 0, stream>>>();
    k_output   <<<N / 256, 256, 0, stream>>>(x, out);
}

// Round 5
// 283.488 us; speedup vs baseline: 1.1602x; 1.1602x over previous
//
#include <hip/hip_runtime.h>
#include <hip/hip_bf16.h>

#define N        8192
#define W        128          // 64-bit words per adjacency row
#define NCLS     5
#define NCOLS    10
#define MIN_PTS  10
#define EPS2     0.0144f      // 0.12^2
#define SENT     N
#define MAXE     (1 << 21)    // 2M edge capacity (~40x expected ~50K)

// ---- persistent device scratch (rewritten every call) ----
__device__ float4             g_pts[N];            // x, y, z, sq
__device__ int                g_cls[N];
__device__ int                g_deg[N];
__device__ int                g_parent[N];         // after k_cc: component-min ROOT directly
__device__ int                g_pointroot[N];      // component-min root per point, SENT if noise
__device__ int                g_rootlabel[N];      // cluster id for root indices
__device__ unsigned long long g_adj[N * W];        // 8 MB adjacency bitmask
__device__ unsigned long long g_coremask[W];
__device__ unsigned long long g_rootmask[NCLS][W];
__device__ int                g_ecnt;
__device__ int2               g_edges[MAXE];       // compact core-core edge list (j < i)

// ---------------- A: per-point setup + scratch init ----------------
__global__ void k_setup(const float* __restrict__ x) {
    int i = blockIdx.x * blockDim.x + threadIdx.x;
    if (i >= N) return;
    const float* r = x + i * NCOLS;
    float c0 = r[0], c1 = r[1], c2 = r[2];
    // argmax over seg cols 5..9, first max wins (matches jnp.argmax)
    float best = r[5]; int bi = 0;
#pragma unroll
    for (int c = 1; c < NCLS; ++c) {
        float v = r[5 + c];
        if (v > best) { best = v; bi = c; }
    }
    // sq = (c0^2 + c1^2) + c2^2 with NO fma contraction (match numpy elementwise+sum)
    float sq = __fadd_rn(__fadd_rn(__fmul_rn(c0, c0), __fmul_rn(c1, c1)), __fmul_rn(c2, c2));
    g_pts[i] = make_float4(c0, c1, c2, sq);
    g_cls[i] = bi;
    g_pointroot[i] = SENT;
    g_rootlabel[i] = -1;
    if (i == 0) g_ecnt = 0;
    if (i < NCLS * W) ((unsigned long long*)g_rootmask)[i] = 0ull;
}

// ---------------- B: adjacency bitmask + degree (one wave per row) ----------------
__global__ void k_adj() {
    int wave = threadIdx.x >> 6;             // 4 waves/block
    int lane = threadIdx.x & 63;
    int i = blockIdx.x * 4 + wave;
    float4 p = g_pts[i];
    int ci = g_cls[i];
    int deg = 0;
    for (int w = 0; w < W; ++w) {
        int j = (w << 6) + lane;             // lane-coalesced column sweep
        float4 q = g_pts[j];
        int cj = g_cls[j];
        // dot as fma chain (BLAS K=3 accumulation); 2*dot exact, one rounding on subtract
        float dot = __builtin_fmaf(p.z, q.z,
                    __builtin_fmaf(p.y, q.y,
                    __builtin_fmaf(p.x, q.x, 0.0f)));
        float d2 = (p.w + q.w) - 2.0f * dot;
        bool adjb = (d2 < EPS2) && (ci == cj);   // diagonal included (d2_ii ~ 0)
        unsigned long long word = __ballot(adjb);
        if (lane == 0) {
            g_adj[i * W + w] = word;
            deg += __popcll(word);
        }
    }
    if (lane == 0) g_deg[i] = deg;
}

// ---------------- C: pack core bitmask (grid-wide ballot) ----------------
__global__ void k_core() {
    int i = blockIdx.x * blockDim.x + threadIdx.x;
    bool c = g_deg[i] >= MIN_PTS;
    unsigned long long m = __ballot(c);
    if ((threadIdx.x & 63) == 0) g_coremask[i >> 6] = m;
}

// ---------------- D1: extract core-core edges (j < i) into compact list ----------------
__global__ void k_edges() {
    __shared__ unsigned long long s_core[W];
    int t = threadIdx.x;
    if (t < W) s_core[t] = g_coremask[t];
    __syncthreads();
    int gid = blockIdx.x * blockDim.x + t;
    int i = gid >> 7, w = gid & 127;
    int jbase = w << 6;
    unsigned long long word = 0ull;
    if (jbase < i && ((s_core[i >> 6] >> (i & 63)) & 1)) {   // i must be core, pair once
        word = g_adj[i * W + w] & s_core[w];
        int lim = i - jbase;
        if (lim < 64) word &= (1ull << lim) - 1;             // keep j < i
    }
    int cnt = __popcll(word);
    // wave-aggregated allocation: inclusive prefix over 64 lanes, one atomicAdd per wave
    int lane = t & 63;
    int pre = cnt;
#pragma unroll
    for (int d = 1; d < 64; d <<= 1) {
        int v = __shfl_up(pre, d);
        if (lane >= d) pre += v;
    }
    int total = __shfl(pre, 63);
    if (total == 0) return;
    int base = 0;
    if (lane == 63) base = atomicAdd(&g_ecnt, total);
    base = __shfl(base, 63);
    int off = base + pre - cnt;                              // exclusive prefix
    while (word) {
        int k = __builtin_ctzll(word);
        word &= word - 1;
        if (off < MAXE) g_edges[off] = make_int2(i, jbase + k);
        ++off;
    }
}

// ---------------- D2: connected components in LDS (single block) ----------------
// Hooking larger root under smaller root => final root of each tree is the
// component minimum (exactly the reference fixpoint's value). Path-halving
// writes are benign races (parent strictly decreases toward an ancestor).
__global__ void __launch_bounds__(1024) k_cc() {
    __shared__ int sp[N];                    // 32 KB parent array
    int t = threadIdx.x;
    for (int i = t; i < N; i += 1024) sp[i] = i;
    __syncthreads();
    volatile int* vsp = sp;
    int ecnt = g_ecnt;
    if (ecnt > MAXE) ecnt = MAXE;
    for (int e = t; e < ecnt; e += 1024) {
        int2 ed = g_edges[e];
        int ra = ed.x, rb = ed.y;
        for (;;) {
            // find roots with path halving
            for (;;) {
                int p = vsp[ra];
                if (p == ra) break;
                int gp = vsp[p];
                if (gp != p) vsp[ra] = gp;
                ra = gp;
            }
            for (;;) {
                int p = vsp[rb];
                if (p == rb) break;
                int gp = vsp[p];
                if (gp != p) vsp[rb] = gp;
                rb = gp;
            }
            if (ra == rb) break;
            int hi = ra > rb ? ra : rb;
            int lo = ra < rb ? ra : rb;
            int old = atomicCAS(&sp[hi], hi, lo);            // hook live root only
            if (old == hi) break;
            ra = old; rb = lo;
        }
    }
    __syncthreads();
    // flatten: g_parent[i] = component-min root (single-load finds downstream)
    for (int i = t; i < N; i += 1024) {
        int r = i, p = sp[r];
        while (p != r) { r = p; p = sp[r]; }
        g_parent[i] = r;
    }
}

// ---------------- E: point roots + root bitmask ----------------
__global__ void k_pointroot() {
    __shared__ unsigned long long s_core[W];
    int t = threadIdx.x;
    if (t < W) s_core[t] = g_coremask[t];
    __syncthreads();
    int gid = blockIdx.x * blockDim.x + t;
    int i = gid >> 7, w = gid & 127;
    bool corei = (s_core[i >> 6] >> (i & 63)) & 1;
    if (corei) {
        if (w == 0) {
            int r = g_parent[i];             // already a root (flattened)
            g_pointroot[i] = r;
            if (r == i)                      // is_root: core && comp==idx
                atomicOr(&g_rootmask[g_cls[i]][i >> 6], 1ull << (i & 63));
        }
        return;
    }
    // border/noise: min over core neighbors' component roots (local min, <=1 atomic)
    unsigned long long word = g_adj[i * W + w] & s_core[w];
    if (!word) return;
    int m = SENT;
    while (word) {
        int k = __builtin_ctzll(word);
        word &= word - 1;
        int r = g_parent[(w << 6) + k];      // single load, no chain
        m = m < r ? m : r;
    }
    atomicMin(&g_pointroot[i], m);
}

// ---------------- G: cluster ids = rank of root key (class*N + idx) ----------------
__global__ void k_rootlabel() {
    int i = blockIdx.x * blockDim.x + threadIdx.x;
    if (i >= N) return;
    if (g_deg[i] < MIN_PTS || g_pointroot[i] != i) return;   // roots only
    int c = g_cls[i];
    int cnt = 0;
    for (int cc = 0; cc < c; ++cc)
#pragma unroll 8
        for (int w = 0; w < W; ++w) cnt += __popcll(g_rootmask[cc][w]);
    int wi = i >> 6;
    for (int w = 0; w < wi; ++w) cnt += __popcll(g_rootmask[c][w]);
    cnt += __popcll(g_rootmask[c][wi] & ((1ull << (i & 63)) - 1));
    g_rootlabel[i] = cnt;
}

// ---------------- H: emit outputs ----------------
__global__ void k_output(const float* __restrict__ x, float* __restrict__ out) {
    int i = blockIdx.x * blockDim.x + threadIdx.x;
    if (i >= N) return;
    int pr = g_pointroot[i];
    bool clustered = (pr < SENT);
    float o[6] = {0.f, 0.f, 0.f, 0.f, 0.f, 0.f};
    float lab = -1.0f;
    if (clustered) {
        lab = (float)g_rootlabel[pr];
        const float* r = x + i * NCOLS;
#pragma unroll
        for (int k = 0; k < 5; ++k) o[k] = r[k];
        o[5] = (float)g_cls[i];
    }
    float* orow = out + i * 6;
#pragma unroll
    for (int k = 0; k < 6; ++k) orow[k] = o[k];
    out[N * 6 + i] = lab;                    // labels as f32 (single-dtype flat buffer)
}

extern "C" void kernel_launch(void* const* d_in, const int* in_sizes, int n_in,
                              void* d_out, int out_size, void* d_ws, size_t ws_size,
                              hipStream_t stream) {
    const float* x = (const float*)d_in[0];
    float* out = (float*)d_out;
    (void)in_sizes; (void)n_in; (void)out_size; (void)d_ws; (void)ws_size;

    k_setup    <<<N / 256, 256, 0, stream>>>(x);
    k_adj      <<<N / 4,   256, 0, stream>>>();        // wave per row
    k_core     <<<N / 256, 256, 0, stream>>>();
    k_edges    <<<(N * W) / 256, 256, 0, stream>>>();
    k_cc       <<<1, 1024, 0, stream>>>();
    k_pointroot<<<(N * W) / 256, 256, 0, stream>>>();
    k_rootlabel<<<N / 256, 256, 0, stream>>>();
    k_output   <<<N / 256, 256, 0, stream>>>(x, out);
}